// Round 1
// baseline (1068.746 us; speedup 1.0000x reference)
//
#include <hip/hip_runtime.h>
#include <hip/hip_bf16.h>

// Problem constants (from reference): FEAT=EMB=HID=64, VOCAB=32, N_GRAPHS=64.
// N and E derived from in_sizes at launch.

// ---------------- CSR build ----------------

__global__ __launch_bounds__(256) void hist_kernel(const int* __restrict__ dst,
                                                   int* __restrict__ deg, int E) {
    int e = blockIdx.x * 256 + threadIdx.x;
    if (e < E) atomicAdd(&deg[dst[e]], 1);
}

// Phase A: per-block inclusive scan (256 elems), write inclusive into incl[],
// block total into bsums[b].
__global__ __launch_bounds__(256) void scan_a(const int* __restrict__ deg,
                                              int* __restrict__ incl,
                                              int* __restrict__ bsums, int N) {
    __shared__ int tmp[256];
    int i = blockIdx.x * 256 + threadIdx.x;
    int v = (i < N) ? deg[i] : 0;
    tmp[threadIdx.x] = v;
    __syncthreads();
    for (int off = 1; off < 256; off <<= 1) {
        int t = (threadIdx.x >= off) ? tmp[threadIdx.x - off] : 0;
        __syncthreads();
        tmp[threadIdx.x] += t;
        __syncthreads();
    }
    if (i < N) incl[i] = tmp[threadIdx.x];
    if (threadIdx.x == 255) bsums[blockIdx.x] = tmp[255];
}

// Phase B: single block, exclusive scan of block sums (nb <= 512).
__global__ __launch_bounds__(512) void scan_b(int* __restrict__ bsums, int nb) {
    __shared__ int tmp[512];
    int t = threadIdx.x;
    int v = (t < nb) ? bsums[t] : 0;
    tmp[t] = v;
    __syncthreads();
    for (int off = 1; off < 512; off <<= 1) {
        int u = (t >= off) ? tmp[t - off] : 0;
        __syncthreads();
        tmp[t] += u;
        __syncthreads();
    }
    if (t < nb) bsums[t] = tmp[t] - v;  // exclusive
}

// Phase C: rowptr[i] = incl[i] - deg[i] + bsums[b]; cursor[i] = rowptr[i];
// last element writes rowptr[N] = E.
__global__ __launch_bounds__(256) void scan_c(const int* __restrict__ deg,
                                              int* __restrict__ rowptr,  // holds incl on entry
                                              int* __restrict__ cursor,
                                              const int* __restrict__ bsums, int N) {
    int i = blockIdx.x * 256 + threadIdx.x;
    if (i < N) {
        int d = deg[i];
        int excl = rowptr[i] - d + bsums[blockIdx.x];
        rowptr[i] = excl;
        cursor[i] = excl;
        if (i == N - 1) rowptr[N] = excl + d;
    }
}

__global__ __launch_bounds__(256) void scatter_kernel(const int* __restrict__ src,
                                                      const int* __restrict__ dst,
                                                      int* __restrict__ cursor,
                                                      int* __restrict__ bucket, int E) {
    int e = blockIdx.x * 256 + threadIdx.x;
    if (e < E) {
        int d = dst[e];
        int pos = atomicAdd(&cursor[d], 1);
        bucket[pos] = src[e];
    }
}

// ---------------- Fused RGCN layer ----------------
// out[i] = relu( (mean_{j in N(i)} x[j]) @ W + x[i] @ root + b )
// One wave per node; lane = output/input feature index.
__global__ __launch_bounds__(256) void rgcn_fused(const float* __restrict__ xin,
                                                  const int* __restrict__ rowptr,
                                                  const int* __restrict__ bucket,
                                                  const float* __restrict__ W,
                                                  const float* __restrict__ R,
                                                  const float* __restrict__ b,
                                                  float* __restrict__ out, int N) {
    __shared__ float Wl[4096];
    __shared__ float Rl[4096];
    __shared__ float bl[64];
    for (int t = threadIdx.x; t < 4096; t += 256) {
        Wl[t] = W[t];
        Rl[t] = R[t];
    }
    if (threadIdx.x < 64) bl[threadIdx.x] = b[threadIdx.x];
    __syncthreads();

    const int lane = threadIdx.x & 63;
    const int wid = threadIdx.x >> 6;
    const int gw = blockIdx.x * 4 + wid;
    const int nw = gridDim.x * 4;

    for (int i = gw; i < N; i += nw) {
        const int r0 = rowptr[i];
        const int deg = rowptr[i + 1] - r0;
        float acc = 0.f;
        for (int base = 0; base < deg; base += 64) {
            int m = deg - base;
            if (m > 64) m = 64;
            int s = (lane < m) ? bucket[r0 + base + lane] : 0;
            for (int j = 0; j < m; ++j) {
                int sj = __shfl(s, j);
                acc += xin[(long)sj * 64 + lane];
            }
        }
        const float inv = 1.0f / (float)(deg > 0 ? deg : 1);
        const float av = acc * inv;              // aggregated-mean feature `lane`
        const float xv = xin[(long)i * 64 + lane];  // self feature `lane`
        float o = bl[lane];
#pragma unroll
        for (int k = 0; k < 64; ++k) {
            o += __shfl(av, k) * Wl[k * 64 + lane];
            o += __shfl(xv, k) * Rl[k * 64 + lane];
        }
        out[(long)i * 64 + lane] = fmaxf(o, 0.f);
    }
}

// ---------------- Pooling (batch is sorted) ----------------
// One wave per 64-node chunk; flush partial sums at graph boundaries.
__global__ __launch_bounds__(64) void pool_kernel(const float* __restrict__ h,
                                                  const int* __restrict__ batch,
                                                  float* __restrict__ pooled,
                                                  float* __restrict__ cntg, int N) {
    const int lane = threadIdx.x;
    const int n0 = blockIdx.x * 64;
    int m = N - n0;
    if (m > 64) m = 64;
    int gl = (lane < m) ? batch[n0 + lane] : -1;
    int cur = __shfl(gl, 0);
    float acc = 0.f;
    int cnt = 0;
    for (int j = 0; j < m; ++j) {
        int g = __shfl(gl, j);
        if (g != cur) {
            atomicAdd(&pooled[cur * 64 + lane], acc);
            if (lane == 0) atomicAdd(&cntg[cur], (float)cnt);
            acc = 0.f;
            cnt = 0;
            cur = g;
        }
        acc += h[(long)(n0 + j) * 64 + lane];
        cnt++;
    }
    atomicAdd(&pooled[cur * 64 + lane], acc);
    if (lane == 0) atomicAdd(&cntg[cur], (float)cnt);
}

// ---------------- Heads: pooled-mean -> hidden/cell -> logits -> log_softmax ----------------
__global__ __launch_bounds__(256) void head_kernel(const float* __restrict__ pooled,
                                                   const float* __restrict__ cntg,
                                                   const float* __restrict__ Wh,
                                                   const float* __restrict__ bh,
                                                   const float* __restrict__ Wc,
                                                   const float* __restrict__ bc,
                                                   const float* __restrict__ Wo,
                                                   const float* __restrict__ bo,
                                                   float* __restrict__ out) {
    __shared__ float pm[4096];   // pooled mean [64][64]
    __shared__ float hid[4096];  // hidden [64][64]
    __shared__ float lg[2048];   // pre-softmax logits [64][32]
    const int t = threadIdx.x;

    for (int idx = t; idx < 4096; idx += 256) {
        int g = idx >> 6;
        float c = cntg[g];
        c = (c > 1.f) ? c : 1.f;
        pm[idx] = pooled[idx] / c;
    }
    __syncthreads();

    for (int idx = t; idx < 4096; idx += 256) {
        int g = idx >> 6, o = idx & 63;
        float ah = bh[o], ac = bc[o];
        for (int k = 0; k < 64; ++k) {
            float p = pm[(g << 6) + k];
            ah += p * Wh[k * 64 + o];
            ac += p * Wc[k * 64 + o];
        }
        hid[idx] = ah;
        out[2048 + idx] = ah;  // hidden
        out[6144 + idx] = ac;  // cell
    }
    __syncthreads();

    for (int idx = t; idx < 2048; idx += 256) {
        int g = idx >> 5, v = idx & 31;
        float a = bo[v];
        for (int k = 0; k < 64; ++k) a += hid[(g << 6) + k] * Wo[k * 32 + v];
        lg[idx] = a;
    }
    __syncthreads();

    if (t < 64) {
        float mx = -3.4e38f;
        for (int v = 0; v < 32; ++v) mx = fmaxf(mx, lg[(t << 5) + v]);
        float s = 0.f;
        for (int v = 0; v < 32; ++v) s += expf(lg[(t << 5) + v] - mx);
        float lse = mx + logf(s);
        for (int v = 0; v < 32; ++v) out[(t << 5) + v] = lg[(t << 5) + v] - lse;
    }
}

extern "C" void kernel_launch(void* const* d_in, const int* in_sizes, int n_in,
                              void* d_out, int out_size, void* d_ws, size_t ws_size,
                              hipStream_t stream) {
    const float* x = (const float*)d_in[0];
    const int* ei = (const int*)d_in[1];
    const int* batch = (const int*)d_in[2];
    const float* W1 = (const float*)d_in[3];
    const float* root1 = (const float*)d_in[4];
    const float* b1 = (const float*)d_in[5];
    const float* W2 = (const float*)d_in[6];
    const float* root2 = (const float*)d_in[7];
    const float* b2 = (const float*)d_in[8];
    const float* Wh = (const float*)d_in[9];
    const float* bh = (const float*)d_in[10];
    const float* Wc = (const float*)d_in[11];
    const float* bc = (const float*)d_in[12];
    const float* Wo = (const float*)d_in[13];
    const float* bo = (const float*)d_in[14];
    float* out = (float*)d_out;

    const int N = in_sizes[0] / 64;
    const int E = in_sizes[1] / 2;
    const int* srcp = ei;
    const int* dstp = ei + E;

    // Workspace layout (256B aligned slices)
    char* ws = (char*)d_ws;
    size_t off = 0;
    auto alloc = [&](size_t bytes) -> void* {
        void* p = ws + off;
        off += (bytes + 255) & ~(size_t)255;
        return p;
    };
    int* deg = (int*)alloc((size_t)N * 4);
    int* rowptr = (int*)alloc((size_t)(N + 1) * 4);
    int* cursor = (int*)alloc((size_t)N * 4);
    int* bsums = (int*)alloc(512 * 4);
    int* bucket = (int*)alloc((size_t)E * 4);
    float* h1 = (float*)alloc((size_t)N * 64 * 4);
    float* h2 = (float*)alloc((size_t)N * 64 * 4);
    float* pooled = (float*)alloc((4096 + 64) * 4);  // pooled + cntg contiguous
    float* cntg = pooled + 4096;

    const int nbN = (N + 255) / 256;   // scan blocks (391 for N=100000, fits scan_b's 512)
    const int nbE = (E + 255) / 256;

    hipMemsetAsync(deg, 0, (size_t)N * 4, stream);
    hipMemsetAsync(pooled, 0, (4096 + 64) * 4, stream);

    hist_kernel<<<nbE, 256, 0, stream>>>(dstp, deg, E);
    scan_a<<<nbN, 256, 0, stream>>>(deg, rowptr, bsums, N);
    scan_b<<<1, 512, 0, stream>>>(bsums, nbN);
    scan_c<<<nbN, 256, 0, stream>>>(deg, rowptr, cursor, bsums, N);
    scatter_kernel<<<nbE, 256, 0, stream>>>(srcp, dstp, cursor, bucket, E);

    rgcn_fused<<<2048, 256, 0, stream>>>(x, rowptr, bucket, W1, root1, b1, h1, N);
    rgcn_fused<<<2048, 256, 0, stream>>>(h1, rowptr, bucket, W2, root2, b2, h2, N);

    pool_kernel<<<(N + 63) / 64, 64, 0, stream>>>(h2, batch, pooled, cntg, N);
    head_kernel<<<1, 256, 0, stream>>>(pooled, cntg, Wh, bh, Wc, bc, Wo, bo, out);
}

// Round 2
// 934.230 us; speedup vs baseline: 1.1440x; 1.1440x over previous
//
#include <hip/hip_runtime.h>
#include <hip/hip_bf16.h>

// FEAT=EMB=HID=64, VOCAB=32, N_GRAPHS=64. N,E from in_sizes.

// ---------------- CSR build ----------------

__global__ __launch_bounds__(256) void hist_kernel(const int* __restrict__ dst,
                                                   int* __restrict__ deg, int E) {
    int e = blockIdx.x * 256 + threadIdx.x;
    if (e < E) atomicAdd(&deg[dst[e]], 1);
}

__global__ __launch_bounds__(256) void scan_a(const int* __restrict__ deg,
                                              int* __restrict__ incl,
                                              int* __restrict__ bsums, int N) {
    __shared__ int tmp[256];
    int i = blockIdx.x * 256 + threadIdx.x;
    int v = (i < N) ? deg[i] : 0;
    tmp[threadIdx.x] = v;
    __syncthreads();
    for (int off = 1; off < 256; off <<= 1) {
        int t = (threadIdx.x >= off) ? tmp[threadIdx.x - off] : 0;
        __syncthreads();
        tmp[threadIdx.x] += t;
        __syncthreads();
    }
    if (i < N) incl[i] = tmp[threadIdx.x];
    if (threadIdx.x == 255) bsums[blockIdx.x] = tmp[255];
}

__global__ __launch_bounds__(512) void scan_b(int* __restrict__ bsums, int nb) {
    __shared__ int tmp[512];
    int t = threadIdx.x;
    int v = (t < nb) ? bsums[t] : 0;
    tmp[t] = v;
    __syncthreads();
    for (int off = 1; off < 512; off <<= 1) {
        int u = (t >= off) ? tmp[t - off] : 0;
        __syncthreads();
        tmp[t] += u;
        __syncthreads();
    }
    if (t < nb) bsums[t] = tmp[t] - v;  // exclusive
}

__global__ __launch_bounds__(256) void scan_c(const int* __restrict__ deg,
                                              int* __restrict__ rowptr,  // incl on entry
                                              int* __restrict__ cursor,
                                              const int* __restrict__ bsums, int N) {
    int i = blockIdx.x * 256 + threadIdx.x;
    if (i < N) {
        int d = deg[i];
        int excl = rowptr[i] - d + bsums[blockIdx.x];
        rowptr[i] = excl;
        cursor[i] = excl;
        if (i == N - 1) rowptr[N] = excl + d;
    }
}

__global__ __launch_bounds__(256) void scatter_kernel(const int* __restrict__ src,
                                                      const int* __restrict__ dst,
                                                      int* __restrict__ cursor,
                                                      int* __restrict__ bucket, int E) {
    int e = blockIdx.x * 256 + threadIdx.x;
    if (e < E) {
        int d = dst[e];
        int pos = atomicAdd(&cursor[d], 1);
        bucket[pos] = src[e];
    }
}

// ---------------- Fused RGCN layer ----------------
// out[i] = relu( (mean_{j in N(i)} x[j]) @ W + x[i] @ root + b )
// One wave per node. Lanes split 16 (float4 feature slot f) x 4 (edge group g):
// one float4 load instruction gathers 4 edge-rows at once; 2x unrolled = 8 edges
// and 2 independent loads in flight per step (vs 1 scalar-load-per-edge before).
__global__ __launch_bounds__(256, 4) void rgcn_fused(const float* __restrict__ xin,
                                                     const int* __restrict__ rowptr,
                                                     const int* __restrict__ bucket,
                                                     const float* __restrict__ W,
                                                     const float* __restrict__ R,
                                                     const float* __restrict__ b,
                                                     float* __restrict__ out, int N) {
    __shared__ float Wl[4096];
    __shared__ float Rl[4096];
    __shared__ float bl[64];
    for (int t = threadIdx.x; t < 4096; t += 256) {
        Wl[t] = W[t];
        Rl[t] = R[t];
    }
    if (threadIdx.x < 64) bl[threadIdx.x] = b[threadIdx.x];
    __syncthreads();

    const int lane = threadIdx.x & 63;
    const int g = lane >> 4;   // edge group 0..3
    const int f = lane & 15;   // float4 slot: features 4f..4f+3
    const int wid = threadIdx.x >> 6;
    const int gw = blockIdx.x * 4 + wid;
    const int nw = gridDim.x * 4;

    for (int i = gw; i < N; i += nw) {
        const int r0 = rowptr[i];
        const int deg = rowptr[i + 1] - r0;
        float4 acc = {0.f, 0.f, 0.f, 0.f};
        for (int base = 0; base < deg; base += 64) {
            int m = deg - base;
            if (m > 64) m = 64;
            int s = (lane < m) ? bucket[r0 + base + lane] : 0;  // ids for this chunk
            const int steps = (m + 3) >> 2;  // 4 edges per step
            int t = 0;
            for (; t + 2 <= steps; t += 2) {
                const int e0 = t * 4 + g, e1 = e0 + 4;
                const int s0 = __shfl(s, e0);
                const int s1 = __shfl(s, e1);
                const float w0 = (e0 < m) ? 1.f : 0.f;
                const float w1 = (e1 < m) ? 1.f : 0.f;
                const float4 v0 = *(const float4*)&xin[(size_t)s0 * 64 + f * 4];
                const float4 v1 = *(const float4*)&xin[(size_t)s1 * 64 + f * 4];
                acc.x += v0.x * w0; acc.y += v0.y * w0;
                acc.z += v0.z * w0; acc.w += v0.w * w0;
                acc.x += v1.x * w1; acc.y += v1.y * w1;
                acc.z += v1.z * w1; acc.w += v1.w * w1;
            }
            for (; t < steps; ++t) {
                const int e0 = t * 4 + g;
                const int s0 = __shfl(s, e0);
                const float w0 = (e0 < m) ? 1.f : 0.f;
                const float4 v0 = *(const float4*)&xin[(size_t)s0 * 64 + f * 4];
                acc.x += v0.x * w0; acc.y += v0.y * w0;
                acc.z += v0.z * w0; acc.w += v0.w * w0;
            }
        }
        // reduce across the 4 edge groups
        acc.x += __shfl_xor(acc.x, 16); acc.y += __shfl_xor(acc.y, 16);
        acc.z += __shfl_xor(acc.z, 16); acc.w += __shfl_xor(acc.w, 16);
        acc.x += __shfl_xor(acc.x, 32); acc.y += __shfl_xor(acc.y, 32);
        acc.z += __shfl_xor(acc.z, 32); acc.w += __shfl_xor(acc.w, 32);

        const float inv = 1.0f / (float)(deg > 0 ? deg : 1);
        float4 av;
        av.x = acc.x * inv; av.y = acc.y * inv; av.z = acc.z * inv; av.w = acc.w * inv;
        const float4 xv = *(const float4*)&xin[(size_t)i * 64 + f * 4];

        float o = bl[lane];
#pragma unroll
        for (int k4 = 0; k4 < 16; ++k4) {
            const float ax = __shfl(av.x, k4), ay = __shfl(av.y, k4);
            const float az = __shfl(av.z, k4), aw = __shfl(av.w, k4);
            const float xx = __shfl(xv.x, k4), xy = __shfl(xv.y, k4);
            const float xz = __shfl(xv.z, k4), xw = __shfl(xv.w, k4);
            o += ax * Wl[(k4 * 4 + 0) * 64 + lane];
            o += ay * Wl[(k4 * 4 + 1) * 64 + lane];
            o += az * Wl[(k4 * 4 + 2) * 64 + lane];
            o += aw * Wl[(k4 * 4 + 3) * 64 + lane];
            o += xx * Rl[(k4 * 4 + 0) * 64 + lane];
            o += xy * Rl[(k4 * 4 + 1) * 64 + lane];
            o += xz * Rl[(k4 * 4 + 2) * 64 + lane];
            o += xw * Rl[(k4 * 4 + 3) * 64 + lane];
        }
        out[(size_t)i * 64 + lane] = fmaxf(o, 0.f);
    }
}

// ---------------- Pooling (batch sorted): bounds + per-graph block sum ----------
__global__ __launch_bounds__(128) void graph_bounds(const int* __restrict__ batch,
                                                    int* __restrict__ gstart, int N) {
    int t = threadIdx.x;
    if (t > 64) return;
    if (t == 64) { gstart[64] = N; return; }
    int lo = 0, hi = N;
    while (lo < hi) {
        int mid = (lo + hi) >> 1;
        if (batch[mid] < t) lo = mid + 1; else hi = mid;
    }
    gstart[t] = lo;
}

__global__ __launch_bounds__(256) void pool_kernel(const float* __restrict__ h,
                                                   const int* __restrict__ gstart,
                                                   float* __restrict__ pooled) {
    __shared__ float red[16][64];
    const int gph = blockIdx.x;
    const int r0 = gstart[gph], r1 = gstart[gph + 1];
    const int f = threadIdx.x & 15;
    const int r = threadIdx.x >> 4;
    float4 acc = {0.f, 0.f, 0.f, 0.f};
    for (int row = r0 + r; row < r1; row += 16) {
        const float4 v = *(const float4*)&h[(size_t)row * 64 + f * 4];
        acc.x += v.x; acc.y += v.y; acc.z += v.z; acc.w += v.w;
    }
    red[r][f * 4 + 0] = acc.x; red[r][f * 4 + 1] = acc.y;
    red[r][f * 4 + 2] = acc.z; red[r][f * 4 + 3] = acc.w;
    __syncthreads();
    if (threadIdx.x < 64) {
        float s = 0.f;
        for (int j = 0; j < 16; ++j) s += red[j][threadIdx.x];
        const int cnt = r1 - r0;
        const float invc = 1.0f / (float)(cnt > 0 ? cnt : 1);
        pooled[gph * 64 + threadIdx.x] = s * invc;  // mean directly
    }
}

// ---------------- Heads ----------------
__global__ __launch_bounds__(256) void head_kernel(const float* __restrict__ pooled,
                                                   const float* __restrict__ Wh,
                                                   const float* __restrict__ bh,
                                                   const float* __restrict__ Wc,
                                                   const float* __restrict__ bc,
                                                   const float* __restrict__ Wo,
                                                   const float* __restrict__ bo,
                                                   float* __restrict__ out) {
    __shared__ float pm[4096];
    __shared__ float hid[4096];
    __shared__ float lg[2048];
    const int t = threadIdx.x;

    for (int idx = t; idx < 4096; idx += 256) pm[idx] = pooled[idx];
    __syncthreads();

    for (int idx = t; idx < 4096; idx += 256) {
        int g = idx >> 6, o = idx & 63;
        float ah = bh[o], ac = bc[o];
        for (int k = 0; k < 64; ++k) {
            float p = pm[(g << 6) + k];
            ah += p * Wh[k * 64 + o];
            ac += p * Wc[k * 64 + o];
        }
        hid[idx] = ah;
        out[2048 + idx] = ah;  // hidden
        out[6144 + idx] = ac;  // cell
    }
    __syncthreads();

    for (int idx = t; idx < 2048; idx += 256) {
        int g = idx >> 5, v = idx & 31;
        float a = bo[v];
        for (int k = 0; k < 64; ++k) a += hid[(g << 6) + k] * Wo[k * 32 + v];
        lg[idx] = a;
    }
    __syncthreads();

    if (t < 64) {
        float mx = -3.4e38f;
        for (int v = 0; v < 32; ++v) mx = fmaxf(mx, lg[(t << 5) + v]);
        float s = 0.f;
        for (int v = 0; v < 32; ++v) s += expf(lg[(t << 5) + v] - mx);
        float lse = mx + logf(s);
        for (int v = 0; v < 32; ++v) out[(t << 5) + v] = lg[(t << 5) + v] - lse;
    }
}

extern "C" void kernel_launch(void* const* d_in, const int* in_sizes, int n_in,
                              void* d_out, int out_size, void* d_ws, size_t ws_size,
                              hipStream_t stream) {
    const float* x = (const float*)d_in[0];
    const int* ei = (const int*)d_in[1];
    const int* batch = (const int*)d_in[2];
    const float* W1 = (const float*)d_in[3];
    const float* root1 = (const float*)d_in[4];
    const float* b1 = (const float*)d_in[5];
    const float* W2 = (const float*)d_in[6];
    const float* root2 = (const float*)d_in[7];
    const float* b2 = (const float*)d_in[8];
    const float* Wh = (const float*)d_in[9];
    const float* bh = (const float*)d_in[10];
    const float* Wc = (const float*)d_in[11];
    const float* bc = (const float*)d_in[12];
    const float* Wo = (const float*)d_in[13];
    const float* bo = (const float*)d_in[14];
    float* out = (float*)d_out;

    const int N = in_sizes[0] / 64;
    const int E = in_sizes[1] / 2;
    const int* srcp = ei;
    const int* dstp = ei + E;

    char* ws = (char*)d_ws;
    size_t off = 0;
    auto alloc = [&](size_t bytes) -> void* {
        void* p = ws + off;
        off += (bytes + 255) & ~(size_t)255;
        return p;
    };
    int* deg = (int*)alloc((size_t)N * 4);
    int* rowptr = (int*)alloc((size_t)(N + 1) * 4);
    int* cursor = (int*)alloc((size_t)N * 4);
    int* bsums = (int*)alloc(512 * 4);
    int* bucket = (int*)alloc((size_t)E * 4);
    float* h1 = (float*)alloc((size_t)N * 64 * 4);
    float* h2 = (float*)alloc((size_t)N * 64 * 4);
    float* pooled = (float*)alloc(4096 * 4);
    int* gstart = (int*)alloc(65 * 4);

    const int nbN = (N + 255) / 256;
    const int nbE = (E + 255) / 256;

    hipMemsetAsync(deg, 0, (size_t)N * 4, stream);

    hist_kernel<<<nbE, 256, 0, stream>>>(dstp, deg, E);
    scan_a<<<nbN, 256, 0, stream>>>(deg, rowptr, bsums, N);
    scan_b<<<1, 512, 0, stream>>>(bsums, nbN);
    scan_c<<<nbN, 256, 0, stream>>>(deg, rowptr, cursor, bsums, N);
    scatter_kernel<<<nbE, 256, 0, stream>>>(srcp, dstp, cursor, bucket, E);

    rgcn_fused<<<2048, 256, 0, stream>>>(x, rowptr, bucket, W1, root1, b1, h1, N);
    rgcn_fused<<<2048, 256, 0, stream>>>(h1, rowptr, bucket, W2, root2, b2, h2, N);

    graph_bounds<<<1, 128, 0, stream>>>(batch, gstart, N);
    pool_kernel<<<64, 256, 0, stream>>>(h2, gstart, pooled);
    head_kernel<<<1, 256, 0, stream>>>(pooled, Wh, bh, Wc, bc, Wo, bo, out);
}